// Round 3
// baseline (2045.958 us; speedup 1.0000x reference)
//
#include <hip/hip_runtime.h>

#define TT 256
#define BB 4096

__device__ __forceinline__ float sigm(float x) {
  float e = __expf(-x);
  return __builtin_amdgcn_rcpf(1.0f + e);
}

__device__ __forceinline__ float tanhx(float x) {
  x = fminf(15.0f, fmaxf(-15.0f, x));
  float e = __expf(-2.0f * x);
  return (1.0f - e) * __builtin_amdgcn_rcpf(1.0f + e);
}

#define DOT4(acc, wv, xv)                 \
  do {                                    \
    acc = fmaf((wv).x, (xv).x, acc);      \
    acc = fmaf((wv).y, (xv).y, acc);      \
    acc = fmaf((wv).z, (xv).z, acc);      \
    acc = fmaf((wv).w, (xv).w, acc);      \
  } while (0)

// Block = 128 threads (2 waves). Wave 0 = forward layer-2 dir, wave 1 = backward.
// Block owns batch elements b0, b0+1 end-to-end:
//   phase 1: layer-1 GRU (H1=16) per element -> out1 in LDS [2][256][16]
//   phase 2: layer-2 GRU (H2=64), lane l owns hidden unit l, E=2 elements/wave
//   phase 3: h_fwd + h_bwd -> 64->32->8 MLP, write z.
__global__ __launch_bounds__(128, 2) void gru_fused(
    const float* __restrict__ xin,    // [B][T][2]
    const float* __restrict__ wih1,   // [48][2]
    const float* __restrict__ whh1,   // [48][16]
    const float* __restrict__ bih1,   // [48]
    const float* __restrict__ bhh1,   // [48]
    const float* __restrict__ wihf,   // [192][16]
    const float* __restrict__ whhf,   // [192][64]
    const float* __restrict__ bihf,   // [192]
    const float* __restrict__ bhhf,   // [192]
    const float* __restrict__ wihb,
    const float* __restrict__ whhb,
    const float* __restrict__ bihb,
    const float* __restrict__ bhhb,
    const float* __restrict__ W1,     // [32][64]
    const float* __restrict__ b1,     // [32]
    const float* __restrict__ W2,     // [8][32]
    const float* __restrict__ b2,     // [8]
    float* __restrict__ zout)         // [B][8]
{
  __shared__ __align__(16) float out1L[2][TT][16];  // 32 KB: layer-1 outputs per element
  __shared__ __align__(16) float hs[2][2][64];      // [dir][elem][unit] running h of layer 2
  __shared__ __align__(16) float hl1[2][16];        // layer-1 running h per element
  __shared__ __align__(16) float ys[2][32];         // MLP hidden

  const int tid = threadIdx.x;
  const int w   = tid >> 6;   // wave: 0=fwd, 1=bwd (also element index in phases 1,3)
  const int l   = tid & 63;
  const int b0  = blockIdx.x * 2;

  // ---------------- phase 1: layer-1 GRU for element b0 + w ----------------
  if (l < 16) {
    float wr[16], wz[16], wn[16];
#pragma unroll
    for (int j = 0; j < 16; ++j) {
      wr[j] = whh1[l * 16 + j];
      wz[j] = whh1[(16 + l) * 16 + j];
      wn[j] = whh1[(32 + l) * 16 + j];
    }
    const float wir0 = wih1[2 * l],        wir1 = wih1[2 * l + 1];
    const float wiz0 = wih1[2 * (16 + l)], wiz1 = wih1[2 * (16 + l) + 1];
    const float win0 = wih1[2 * (32 + l)], win1 = wih1[2 * (32 + l) + 1];
    const float br  = bih1[l] + bhh1[l];
    const float bz  = bih1[16 + l] + bhh1[16 + l];
    const float bin = bih1[32 + l];
    const float bhn = bhh1[32 + l];

    const int b = b0 + w;
    const float2* xp = (const float2*)xin + (size_t)b * TT;

    float h = 0.0f;
    hl1[w][l] = 0.0f;
    for (int t = 0; t < TT; ++t) {
      float2 xv = xp[t];
      float ar = fmaf(wir1, xv.y, fmaf(wir0, xv.x, br));
      float az = fmaf(wiz1, xv.y, fmaf(wiz0, xv.x, bz));
      float an = fmaf(win1, xv.y, fmaf(win0, xv.x, bin));
      float hr = 0.f, hz = 0.f, hn = bhn;
#pragma unroll
      for (int j = 0; j < 16; ++j) {
        float hj = hl1[w][j];
        hr = fmaf(wr[j], hj, hr);
        hz = fmaf(wz[j], hj, hz);
        hn = fmaf(wn[j], hj, hn);
      }
      float r = sigm(ar + hr);
      float z = sigm(az + hz);
      float n = tanhx(fmaf(r, hn, an));
      h = fmaf(z, h - n, n);   // (1-z)*n + z*h
      hl1[w][l] = h;
      out1L[w][t][l] = h;
    }
  }
  __syncthreads();

  // ---------------- phase 2: layer-2 GRU (dir = w), lane l = unit l ----------------
  const float* wih = w ? wihb : wihf;
  const float* whh = w ? whhb : whhf;
  const float* bih = w ? bihb : bihf;
  const float* bhh = w ? bhhb : bhhf;

  // W_hh rows l (r), 64+l (z), 128+l (n): 192 fp32 in VGPRs.
  float4 wr2[16], wz2[16], wn2[16];
  {
    const float4* whh4 = (const float4*)whh;
#pragma unroll
    for (int j4 = 0; j4 < 16; ++j4) {
      wr2[j4] = whh4[l * 16 + j4];
      wz2[j4] = whh4[(64 + l) * 16 + j4];
      wn2[j4] = whh4[(128 + l) * 16 + j4];
    }
  }
  const float br2  = bih[l] + bhh[l];
  const float bz2  = bih[64 + l] + bhh[64 + l];
  const float bin2 = bih[128 + l];
  const float bhn2 = bhh[128 + l];

  const float4* wih4 = (const float4*)wih;  // [192 rows][4 float4]

  float h0 = 0.f, h1 = 0.f;
  hs[w][0][l] = 0.f;
  hs[w][1][l] = 0.f;

#pragma unroll 1
  for (int t = 0; t < TT; ++t) {
    // anti-LICM fence: keeps the per-step W_ih loads in the loop (L1-resident)
    // instead of hoisted into 48 extra VGPRs that would spill under the 256 cap.
    asm volatile("" ::: "memory");
    const int te = w ? (TT - 1 - t) : t;
    const float4* x0p = (const float4*)&out1L[0][te][0];
    const float4* x1p = (const float4*)&out1L[1][te][0];

    // input projection (x uniform per element; W_ih rows from global/L1)
    float ar0 = br2, az0 = bz2, an0 = bin2;
    float ar1 = br2, az1 = bz2, an1 = bin2;
#pragma unroll
    for (int i4 = 0; i4 < 4; ++i4) {
      const float4 wrv = wih4[l * 4 + i4];
      const float4 wzv = wih4[(64 + l) * 4 + i4];
      const float4 wnv = wih4[(128 + l) * 4 + i4];
      const float4 xa = x0p[i4];
      const float4 xb = x1p[i4];
      DOT4(ar0, wrv, xa); DOT4(az0, wzv, xa); DOT4(an0, wnv, xa);
      DOT4(ar1, wrv, xb); DOT4(az1, wzv, xb); DOT4(an1, wnv, xb);
    }

    // hidden projection: h broadcast from LDS (same-address b128 = conflict-free)
    float hr0 = 0.f, hz0 = 0.f, hn0 = bhn2;
    float hr1 = 0.f, hz1 = 0.f, hn1 = bhn2;
#pragma unroll
    for (int j4 = 0; j4 < 16; ++j4) {
      const float4 ha = *(const float4*)&hs[w][0][j4 * 4];
      const float4 hb = *(const float4*)&hs[w][1][j4 * 4];
      const float4 wrv = wr2[j4];
      const float4 wzv = wz2[j4];
      const float4 wnv = wn2[j4];
      DOT4(hr0, wrv, ha); DOT4(hz0, wzv, ha); DOT4(hn0, wnv, ha);
      DOT4(hr1, wrv, hb); DOT4(hz1, wzv, hb); DOT4(hn1, wnv, hb);
    }

    // gates (r,z,n order; b_hh_n stays inside r*(...))
    {
      float r = sigm(ar0 + hr0);
      float z = sigm(az0 + hz0);
      float n = tanhx(fmaf(r, hn0, an0));
      h0 = fmaf(z, h0 - n, n);
    }
    {
      float r = sigm(ar1 + hr1);
      float z = sigm(az1 + hz1);
      float n = tanhx(fmaf(r, hn1, an1));
      h1 = fmaf(z, h1 - n, n);
    }
    hs[w][0][l] = h0;   // written after all reads of this step; same-wave lgkmcnt orders t+1
    hs[w][1][l] = h1;
  }
  __syncthreads();

  // ---------------- phase 3: h = h_fwd + h_bwd; MLP 64->32->8 ----------------
  const int e  = w;        // wave w finishes element b0+w
  const int bo = b0 + e;
  if (l < 32) {
    float acc = b1[l];
    const float4* w1r = (const float4*)(W1 + l * 64);
#pragma unroll
    for (int j4 = 0; j4 < 16; ++j4) {
      const float4 hv0 = *(const float4*)&hs[0][e][j4 * 4];
      const float4 hv1 = *(const float4*)&hs[1][e][j4 * 4];
      const float4 wv  = w1r[j4];
      acc = fmaf(wv.x, hv0.x + hv1.x, acc);
      acc = fmaf(wv.y, hv0.y + hv1.y, acc);
      acc = fmaf(wv.z, hv0.z + hv1.z, acc);
      acc = fmaf(wv.w, hv0.w + hv1.w, acc);
    }
    ys[e][l] = acc;
  }
  // same-wave LDS write->read: in-order, no barrier needed
  if (l < 8) {
    float acc = b2[l];
#pragma unroll
    for (int j4 = 0; j4 < 8; ++j4) {
      const float4 yv = *(const float4*)&ys[e][j4 * 4];
      const float4 wv = *(const float4*)&W2[l * 32 + j4 * 4];
      DOT4(acc, wv, yv);
    }
    zout[bo * 8 + l] = acc;
  }
}

extern "C" void kernel_launch(void* const* d_in, const int* in_sizes, int n_in,
                              void* d_out, int out_size, void* d_ws, size_t ws_size,
                              hipStream_t stream) {
  const float* all_traj = (const float*)d_in[0];
  const float* w_ih1  = (const float*)d_in[1];
  const float* w_hh1  = (const float*)d_in[2];
  const float* b_ih1  = (const float*)d_in[3];
  const float* b_hh1  = (const float*)d_in[4];
  const float* w_ih2f = (const float*)d_in[5];
  const float* w_hh2f = (const float*)d_in[6];
  const float* b_ih2f = (const float*)d_in[7];
  const float* b_hh2f = (const float*)d_in[8];
  const float* w_ih2b = (const float*)d_in[9];
  const float* w_hh2b = (const float*)d_in[10];
  const float* b_ih2b = (const float*)d_in[11];
  const float* b_hh2b = (const float*)d_in[12];
  const float* W1 = (const float*)d_in[13];
  const float* b1 = (const float*)d_in[14];
  const float* W2 = (const float*)d_in[15];
  const float* b2 = (const float*)d_in[16];
  float* z = (float*)d_out;

  // 2048 blocks x 128 threads: each block = 2 batch elements, both directions + MLP
  gru_fused<<<BB / 2, 128, 0, stream>>>(
      all_traj, w_ih1, w_hh1, b_ih1, b_hh1,
      w_ih2f, w_hh2f, b_ih2f, b_hh2f,
      w_ih2b, w_hh2b, b_ih2b, b_hh2b,
      W1, b1, W2, b2, z);
}

// Round 4
// 1454.653 us; speedup vs baseline: 1.4065x; 1.4065x over previous
//
#include <hip/hip_runtime.h>

#define TT 256
#define BB 4096
#define EPB 4   // batch elements per block

__device__ __forceinline__ float sigm(float x) {
  float e = __expf(-x);
  return __builtin_amdgcn_rcpf(1.0f + e);
}

__device__ __forceinline__ float tanhx(float x) {
  x = fminf(15.0f, fmaxf(-15.0f, x));
  float e = __expf(-2.0f * x);
  return (1.0f - e) * __builtin_amdgcn_rcpf(1.0f + e);
}

#define DOT4(acc, wv, xv)                 \
  do {                                    \
    acc = fmaf((wv).x, (xv).x, acc);      \
    acc = fmaf((wv).y, (xv).y, acc);      \
    acc = fmaf((wv).z, (xv).z, acc);      \
    acc = fmaf((wv).w, (xv).w, acc);      \
  } while (0)

// Block = 128 threads (2 waves), EPB=4 batch elements per block.
// Wave 0 = forward layer-2 dir, wave 1 = backward (each over all 4 elements).
//   phase 1: layer-1 GRU (H1=16); each wave runs 2 elements in 16-lane groups
//   phase 2: layer-2 GRU (H2=64), lane l = unit l; ALL weights VGPR-resident
//            (192 W_hh + 48 W_ih floats/lane), h broadcast via uniform LDS b128
//   phase 3: h_fwd + h_bwd -> 64->32->8 MLP.
// 1 wave/SIMD by design (VGPR ~350): 1024 blocks / (256 CU * 2 blocks) = 2 rounds.
__global__ __launch_bounds__(128, 1) void gru_fused(
    const float* __restrict__ xin,    // [B][T][2]
    const float* __restrict__ wih1,   // [48][2]
    const float* __restrict__ whh1,   // [48][16]
    const float* __restrict__ bih1,   // [48]
    const float* __restrict__ bhh1,   // [48]
    const float* __restrict__ wihf,   // [192][16]
    const float* __restrict__ whhf,   // [192][64]
    const float* __restrict__ bihf,   // [192]
    const float* __restrict__ bhhf,   // [192]
    const float* __restrict__ wihb,
    const float* __restrict__ whhb,
    const float* __restrict__ bihb,
    const float* __restrict__ bhhb,
    const float* __restrict__ W1,     // [32][64]
    const float* __restrict__ b1,     // [32]
    const float* __restrict__ W2,     // [8][32]
    const float* __restrict__ b2,     // [8]
    float* __restrict__ zout)         // [B][8]
{
  __shared__ __align__(16) float out1L[EPB][TT][16];  // 64 KB layer-1 outputs
  __shared__ __align__(16) float hs[2][EPB][64];      // [dir][elem][unit]
  __shared__ __align__(16) float hl1[EPB][16];        // layer-1 running h
  __shared__ __align__(16) float ys[EPB][32];         // MLP hidden

  const int tid = threadIdx.x;
  const int w   = tid >> 6;   // wave: 0=fwd, 1=bwd
  const int l   = tid & 63;
  const int b0  = blockIdx.x * EPB;

  // ---------------- phase 1: layer-1 GRU, 2 elements per wave ----------------
  if (l < 32) {
    const int g = l >> 4;        // lane group within wave
    const int u = l & 15;        // hidden unit
    const int e = w * 2 + g;     // element 0..3

    float wr[16], wz[16], wn[16];
#pragma unroll
    for (int j = 0; j < 16; ++j) {
      wr[j] = whh1[u * 16 + j];
      wz[j] = whh1[(16 + u) * 16 + j];
      wn[j] = whh1[(32 + u) * 16 + j];
    }
    const float wir0 = wih1[2 * u],        wir1 = wih1[2 * u + 1];
    const float wiz0 = wih1[2 * (16 + u)], wiz1 = wih1[2 * (16 + u) + 1];
    const float win0 = wih1[2 * (32 + u)], win1 = wih1[2 * (32 + u) + 1];
    const float br  = bih1[u] + bhh1[u];
    const float bz  = bih1[16 + u] + bhh1[16 + u];
    const float bin = bih1[32 + u];
    const float bhn = bhh1[32 + u];

    const float2* xp = (const float2*)xin + (size_t)(b0 + e) * TT;

    float h = 0.0f;
    hl1[e][u] = 0.0f;
    for (int t = 0; t < TT; ++t) {
      float2 xv = xp[t];
      float ar = fmaf(wir1, xv.y, fmaf(wir0, xv.x, br));
      float az = fmaf(wiz1, xv.y, fmaf(wiz0, xv.x, bz));
      float an = fmaf(win1, xv.y, fmaf(win0, xv.x, bin));
      float hr = 0.f, hz = 0.f, hn = bhn;
#pragma unroll
      for (int j = 0; j < 16; ++j) {
        float hj = hl1[e][j];
        hr = fmaf(wr[j], hj, hr);
        hz = fmaf(wz[j], hj, hz);
        hn = fmaf(wn[j], hj, hn);
      }
      float r = sigm(ar + hr);
      float z = sigm(az + hz);
      float n = tanhx(fmaf(r, hn, an));
      h = fmaf(z, h - n, n);   // (1-z)*n + z*h
      hl1[e][u] = h;
      out1L[e][t][u] = h;
    }
  }
  __syncthreads();

  // ---------------- phase 2: layer-2 GRU (dir = w), lane l = unit l ----------------
  const float* wih = w ? wihb : wihf;
  const float* whh = w ? whhb : whhf;
  const float* bih = w ? bihb : bihf;
  const float* bhh = w ? bhhb : bhhf;

  // W_hh rows l / 64+l / 128+l : 192 fp32, VGPR-resident for the whole scan.
  float4 wr2[16], wz2[16], wn2[16];
  {
    const float4* whh4 = (const float4*)whh;
#pragma unroll
    for (int j4 = 0; j4 < 16; ++j4) {
      wr2[j4] = whh4[l * 16 + j4];
      wz2[j4] = whh4[(64 + l) * 16 + j4];
      wn2[j4] = whh4[(128 + l) * 16 + j4];
    }
  }
  // W_ih rows: 48 fp32, VGPR-resident.
  float4 wir2[4], wiz2[4], win2[4];
  {
    const float4* wih4 = (const float4*)wih;
#pragma unroll
    for (int i4 = 0; i4 < 4; ++i4) {
      wir2[i4] = wih4[l * 4 + i4];
      wiz2[i4] = wih4[(64 + l) * 4 + i4];
      win2[i4] = wih4[(128 + l) * 4 + i4];
    }
  }
  const float br2  = bih[l] + bhh[l];
  const float bz2  = bih[64 + l] + bhh[64 + l];
  const float bin2 = bih[128 + l];
  const float bhn2 = bhh[128 + l];

  float h0 = 0.f, h1 = 0.f, h2 = 0.f, h3 = 0.f;
  hs[w][0][l] = 0.f; hs[w][1][l] = 0.f; hs[w][2][l] = 0.f; hs[w][3][l] = 0.f;

#pragma unroll 1
  for (int t = 0; t < TT; ++t) {
    const int te = w ? (TT - 1 - t) : t;
    const float4* x0p = (const float4*)&out1L[0][te][0];
    const float4* x1p = (const float4*)&out1L[1][te][0];
    const float4* x2p = (const float4*)&out1L[2][te][0];
    const float4* x3p = (const float4*)&out1L[3][te][0];

    // input projection first: pure-register FMAs hide the h write->read turnaround
    float ar0 = br2, az0 = bz2, an0 = bin2;
    float ar1 = br2, az1 = bz2, an1 = bin2;
    float ar2 = br2, az2 = bz2, an2 = bin2;
    float ar3 = br2, az3 = bz2, an3 = bin2;
#pragma unroll
    for (int i4 = 0; i4 < 4; ++i4) {
      const float4 wrv = wir2[i4], wzv = wiz2[i4], wnv = win2[i4];
      const float4 xa = x0p[i4], xb = x1p[i4], xc = x2p[i4], xd = x3p[i4];
      DOT4(ar0, wrv, xa); DOT4(az0, wzv, xa); DOT4(an0, wnv, xa);
      DOT4(ar1, wrv, xb); DOT4(az1, wzv, xb); DOT4(an1, wnv, xb);
      DOT4(ar2, wrv, xc); DOT4(az2, wzv, xc); DOT4(an2, wnv, xc);
      DOT4(ar3, wrv, xd); DOT4(az3, wzv, xd); DOT4(an3, wnv, xd);
    }

    // hidden projection: h broadcast from LDS (uniform-address b128 = conflict-free)
    float hr0 = 0.f, hz0 = 0.f, hn0 = bhn2;
    float hr1 = 0.f, hz1 = 0.f, hn1 = bhn2;
    float hr2 = 0.f, hz2 = 0.f, hn2 = bhn2;
    float hr3 = 0.f, hz3 = 0.f, hn3 = bhn2;
#pragma unroll
    for (int j4 = 0; j4 < 16; ++j4) {
      const float4 ha = *(const float4*)&hs[w][0][j4 * 4];
      const float4 hb = *(const float4*)&hs[w][1][j4 * 4];
      const float4 hc = *(const float4*)&hs[w][2][j4 * 4];
      const float4 hd = *(const float4*)&hs[w][3][j4 * 4];
      const float4 wrv = wr2[j4], wzv = wz2[j4], wnv = wn2[j4];
      DOT4(hr0, wrv, ha); DOT4(hz0, wzv, ha); DOT4(hn0, wnv, ha);
      DOT4(hr1, wrv, hb); DOT4(hz1, wzv, hb); DOT4(hn1, wnv, hb);
      DOT4(hr2, wrv, hc); DOT4(hz2, wzv, hc); DOT4(hn2, wnv, hc);
      DOT4(hr3, wrv, hd); DOT4(hz3, wzv, hd); DOT4(hn3, wnv, hd);
    }

    { float r = sigm(ar0 + hr0), z = sigm(az0 + hz0);
      float n = tanhx(fmaf(r, hn0, an0)); h0 = fmaf(z, h0 - n, n); }
    { float r = sigm(ar1 + hr1), z = sigm(az1 + hz1);
      float n = tanhx(fmaf(r, hn1, an1)); h1 = fmaf(z, h1 - n, n); }
    { float r = sigm(ar2 + hr2), z = sigm(az2 + hz2);
      float n = tanhx(fmaf(r, hn2, an2)); h2 = fmaf(z, h2 - n, n); }
    { float r = sigm(ar3 + hr3), z = sigm(az3 + hz3);
      float n = tanhx(fmaf(r, hn3, an3)); h3 = fmaf(z, h3 - n, n); }

    hs[w][0][l] = h0; hs[w][1][l] = h1; hs[w][2][l] = h2; hs[w][3][l] = h3;
  }
  __syncthreads();

  // ---------------- phase 3: h = h_fwd + h_bwd; MLP 64->32->8 ----------------
  const int e3 = w * 2 + (l >> 5);   // element this half-wave finishes
  const int s  = l & 31;
  const int bo = b0 + e3;
  {
    float acc = b1[s];
    const float4* w1r = (const float4*)(W1 + s * 64);
#pragma unroll
    for (int j4 = 0; j4 < 16; ++j4) {
      const float4 hv0 = *(const float4*)&hs[0][e3][j4 * 4];
      const float4 hv1 = *(const float4*)&hs[1][e3][j4 * 4];
      const float4 wv  = w1r[j4];
      acc = fmaf(wv.x, hv0.x + hv1.x, acc);
      acc = fmaf(wv.y, hv0.y + hv1.y, acc);
      acc = fmaf(wv.z, hv0.z + hv1.z, acc);
      acc = fmaf(wv.w, hv0.w + hv1.w, acc);
    }
    ys[e3][s] = acc;
  }
  // same-wave LDS write->read: in-order, no barrier needed
  if (s < 8) {
    float acc = b2[s];
#pragma unroll
    for (int j4 = 0; j4 < 8; ++j4) {
      const float4 yv = *(const float4*)&ys[e3][j4 * 4];
      const float4 wv = *(const float4*)&W2[s * 32 + j4 * 4];
      DOT4(acc, wv, yv);
    }
    zout[bo * 8 + s] = acc;
  }
}

extern "C" void kernel_launch(void* const* d_in, const int* in_sizes, int n_in,
                              void* d_out, int out_size, void* d_ws, size_t ws_size,
                              hipStream_t stream) {
  const float* all_traj = (const float*)d_in[0];
  const float* w_ih1  = (const float*)d_in[1];
  const float* w_hh1  = (const float*)d_in[2];
  const float* b_ih1  = (const float*)d_in[3];
  const float* b_hh1  = (const float*)d_in[4];
  const float* w_ih2f = (const float*)d_in[5];
  const float* w_hh2f = (const float*)d_in[6];
  const float* b_ih2f = (const float*)d_in[7];
  const float* b_hh2f = (const float*)d_in[8];
  const float* w_ih2b = (const float*)d_in[9];
  const float* w_hh2b = (const float*)d_in[10];
  const float* b_ih2b = (const float*)d_in[11];
  const float* b_hh2b = (const float*)d_in[12];
  const float* W1 = (const float*)d_in[13];
  const float* b1 = (const float*)d_in[14];
  const float* W2 = (const float*)d_in[15];
  const float* b2 = (const float*)d_in[16];
  float* z = (float*)d_out;

  // 1024 blocks x 128 threads: each block = 4 batch elements, both dirs + MLP
  gru_fused<<<BB / EPB, 128, 0, stream>>>(
      all_traj, w_ih1, w_hh1, b_ih1, b_hh1,
      w_ih2f, w_hh2f, b_ih2f, b_hh2f,
      w_ih2b, w_hh2b, b_ih2b, b_hh2b,
      W1, b1, W2, b2, z);
}